// Round 3
// baseline (485.670 us; speedup 1.0000x reference)
//
#include <hip/hip_runtime.h>
#include <math.h>

// Problem constants (B, N, M, V, T fixed by reference)
namespace {
constexpr int kB = 8;
constexpr int kN = 6;        // max_span
constexpr int kM = 64;
constexpr int kV = 32000;
constexpr int kT = 8;        // template_len
constexpr int kS = kN + 1;   // 7
constexpr int kC = 4;        // v-chunks per row (load balancing)
constexpr int kV4 = kV / 4;        // 8000 float4 per row
constexpr int kCV4 = kV4 / kC;     // 2000 float4 per chunk
constexpr int kThreads = 256;
}  // namespace

typedef float f32x4 __attribute__((ext_vector_type(4)));

// ws layout:
//   float pmax[B][T][M][C]   -- per-chunk partial max, written exactly once
//   float v0[B][T][M]        -- value at v==0, written once by the c==0 block
// No init kernel, no atomics needed.

// ---------------------------------------------------------------------------
// Pass 1: per (b,m,c) block, stream chunk c of the `nuse = spans[b]` used
// input rows once. For each t: out_t[m,v] = sum_n w[t][n]*in[n,m,v]
// (+w0[t] at m==0,v==0). Store the t==0 chunk to d_out speculatively
// (statistically the final answer); record per-t chunk max (+ v0).
// ---------------------------------------------------------------------------
template <int NUSE>
__device__ __forceinline__ void pass1_body(const float* __restrict__ in,
                                           const float* __restrict__ tw,  // tmpl + b*T*S
                                           float* __restrict__ orow,      // + chunk offset
                                           int b, int m, int c,
                                           float* __restrict__ pmax,
                                           float* __restrict__ v0g) {
  const int tid = threadIdx.x;
  constexpr int NA = NUSE > 0 ? NUSE : 1;

  float w[kT][NA];
  float w0[kT];
#pragma unroll
  for (int t = 0; t < kT; ++t) {
    w0[t] = tw[t * kS];  // s=0 pad weight (always unmasked since span>=0)
#pragma unroll
    for (int n = 0; n < NUSE; ++n) w[t][n] = tw[t * kS + n + 1];
  }

  const f32x4* rows[NA];
#pragma unroll
  for (int n = 0; n < NUSE; ++n)
    rows[n] = (const f32x4*)(in + ((size_t)(b * kN + n) * kM + m) * kV) +
              (size_t)c * kCV4;

  f32x4* orow4 = (f32x4*)orow;

  float mx[kT], v0[kT];
#pragma unroll
  for (int t = 0; t < kT; ++t) {
    mx[t] = -INFINITY;
    v0[t] = 0.0f;
  }

  const bool headblk = (c == 0);
  for (int v4 = tid; v4 < kCV4; v4 += kThreads) {
    f32x4 x[NA];
#pragma unroll
    for (int n = 0; n < NUSE; ++n) x[n] = __builtin_nontemporal_load(&rows[n][v4]);
    const bool head = headblk && (v4 == 0);  // global v==0 element, tid 0 only
#pragma unroll
    for (int t = 0; t < kT; ++t) {
      float ax = 0.0f, ay = 0.0f, az = 0.0f, aw = 0.0f;
#pragma unroll
      for (int n = 0; n < NUSE; ++n) {
        ax = fmaf(w[t][n], x[n].x, ax);
        ay = fmaf(w[t][n], x[n].y, ay);
        az = fmaf(w[t][n], x[n].z, az);
        aw = fmaf(w[t][n], x[n].w, aw);
      }
      if (head && m == 0) ax += w0[t];  // pad one-hot lands at (m=0,v=0)
      if (head) v0[t] = ax;
      mx[t] = fmaxf(mx[t], fmaxf(fmaxf(ax, ay), fmaxf(az, aw)));
      if (t == 0) {
        f32x4 o = {ax, ay, az, aw};
        __builtin_nontemporal_store(o, &orow4[v4]);
      }
    }
  }

  // Block max reduction per t: wave shuffle, then 4 wave results via LDS.
  __shared__ float red[kT][4];
  const int lane = tid & 63;
  const int wv = tid >> 6;
#pragma unroll
  for (int t = 0; t < kT; ++t) {
    float v = mx[t];
#pragma unroll
    for (int off = 32; off > 0; off >>= 1) v = fmaxf(v, __shfl_xor(v, off, 64));
    if (lane == 0) red[t][wv] = v;
  }
  __syncthreads();
  if (tid == 0) {
#pragma unroll
    for (int t = 0; t < kT; ++t) {
      float bm = fmaxf(fmaxf(red[t][0], red[t][1]), fmaxf(red[t][2], red[t][3]));
      pmax[((b * kT + t) * kM + m) * kC + c] = bm;
      if (headblk) v0g[(b * kT + t) * kM + m] = v0[t];
    }
  }
}

__global__ __launch_bounds__(kThreads) void pass1_kernel(
    const float* __restrict__ in, const float* __restrict__ tmpl,
    const int* __restrict__ spans, float* __restrict__ out,
    float* __restrict__ pmax, float* __restrict__ v0g) {
  const int blk = blockIdx.x;
  const int c = blk & (kC - 1);
  const int m = (blk >> 2) & 63;
  const int b = blk >> 8;
  int span = spans[b];
  int nuse = span < 0 ? 0 : (span > kN ? kN : span);  // rows used: n < span
  const float* tw = tmpl + (size_t)b * kT * kS;
  float* orow = out + (size_t)(b * kM + m) * kV + (size_t)c * kCV4 * 4;
  switch (nuse) {
    case 0: pass1_body<0>(in, tw, orow, b, m, c, pmax, v0g); break;
    case 1: pass1_body<1>(in, tw, orow, b, m, c, pmax, v0g); break;
    case 2: pass1_body<2>(in, tw, orow, b, m, c, pmax, v0g); break;
    case 3: pass1_body<3>(in, tw, orow, b, m, c, pmax, v0g); break;
    case 4: pass1_body<4>(in, tw, orow, b, m, c, pmax, v0g); break;
    case 5: pass1_body<5>(in, tw, orow, b, m, c, pmax, v0g); break;
    case 6: pass1_body<6>(in, tw, orow, b, m, c, pmax, v0g); break;
  }
}

// ---------------------------------------------------------------------------
// Patch: per (b,m) block. lane m' combines the 4 chunk maxes (one float4
// load), flag = (v0 >= max); ballot -> len[t] = first flagged m'. Then the
// tiny sequential scan inline, and:
//   sel t==0  -> row already stored by pass1, return
//   unwritten -> zero the row
//   else      -> recompute the selected (t, src_row) row
// ---------------------------------------------------------------------------
__global__ __launch_bounds__(kThreads) void patch_kernel(
    const float* __restrict__ in, const float* __restrict__ tmpl,
    const int* __restrict__ spans, const float* __restrict__ pmax,
    const float* __restrict__ v0g, float* __restrict__ out) {
  const int blk = blockIdx.x;
  const int b = blk >> 6;
  const int m = blk & 63;
  const int tid = threadIdx.x;
  const int lane = tid & 63;

  __shared__ int slen[kT];
  if (tid < 64) {
#pragma unroll
    for (int t = 0; t < kT; ++t) {
      f32x4 p = *(const f32x4*)&pmax[((b * kT + t) * kM + lane) * kC];
      float bm = fmaxf(fmaxf(p.x, p.y), fmaxf(p.z, p.w));
      float v0 = v0g[(b * kT + t) * kM + lane];
      unsigned long long bal = __ballot(v0 >= bm);
      if (lane == 0) slen[t] = bal ? (int)(__ffsll((long long)bal) - 1) : kM;
    }
  }
  __syncthreads();

  // sequential scan (cheap, every thread redundantly)
  int sel_t = -1, sel_row = 0, idx = 0;
#pragma unroll
  for (int t = 0; t < kT; ++t) {
    int L = slen[t];
    if (L > kM - idx) L = kM - idx;
    if (sel_t < 0 && m >= idx && m < idx + L) {
      sel_t = t;
      sel_row = m - idx;
    }
    idx += L;
  }

  if (sel_t == 0) return;  // t==0 => sel_row == m, already stored by pass1

  float* orow = out + (size_t)(b * kM + m) * kV;
  f32x4* orow4 = (f32x4*)orow;

  if (sel_t < 0) {  // never written by the scan -> zeros
    f32x4 z = {0.0f, 0.0f, 0.0f, 0.0f};
    for (int v4 = tid; v4 < kV4; v4 += kThreads)
      __builtin_nontemporal_store(z, &orow4[v4]);
    return;
  }

  const int t = sel_t;
  const int row = sel_row;
  int span = spans[b];
  int nuse = span < 0 ? 0 : (span > kN ? kN : span);
  const float* tw = tmpl + ((size_t)b * kT + t) * kS;
  const float w0 = tw[0];
  float w[kN];
  for (int n = 0; n < kN; ++n) w[n] = (n < nuse) ? tw[n + 1] : 0.0f;

  const f32x4* rows[kN];
  for (int n = 0; n < kN; ++n)
    rows[n] = (const f32x4*)(in + ((size_t)(b * kN + n) * kM + row) * kV);

  for (int v4 = tid; v4 < kV4; v4 += kThreads) {
    float ax = 0.0f, ay = 0.0f, az = 0.0f, aw = 0.0f;
    for (int n = 0; n < nuse; ++n) {
      f32x4 x = __builtin_nontemporal_load(&rows[n][v4]);
      ax = fmaf(w[n], x.x, ax);
      ay = fmaf(w[n], x.y, ay);
      az = fmaf(w[n], x.z, az);
      aw = fmaf(w[n], x.w, aw);
    }
    if (v4 == 0 && row == 0) ax += w0;
    f32x4 o = {ax, ay, az, aw};
    __builtin_nontemporal_store(o, &orow4[v4]);
  }
}

extern "C" void kernel_launch(void* const* d_in, const int* in_sizes, int n_in,
                              void* d_out, int out_size, void* d_ws,
                              size_t ws_size, hipStream_t stream) {
  const float* in = (const float*)d_in[0];     // [B,N,M,V] f32
  const float* tmpl = (const float*)d_in[1];   // [B,T,N+1] f32
  const int* spans = (const int*)d_in[2];      // [B] i32
  float* out = (float*)d_out;                  // [B,M,V] f32

  float* pmax = (float*)d_ws;                 // B*T*M*C floats
  float* v0g = pmax + kB * kT * kM * kC;      // B*T*M floats

  hipLaunchKernelGGL(pass1_kernel, dim3(kB * kM * kC), dim3(kThreads), 0,
                     stream, in, tmpl, spans, out, pmax, v0g);
  hipLaunchKernelGGL(patch_kernel, dim3(kB * kM), dim3(kThreads), 0, stream,
                     in, tmpl, spans, pmax, v0g, out);
}